// Round 18
// baseline (172.498 us; speedup 1.0000x reference)
//
#include <hip/hip_runtime.h>

typedef _Float16 f16;
typedef __attribute__((ext_vector_type(4))) float f4;
typedef __attribute__((ext_vector_type(4))) _Float16 h4;
typedef __attribute__((ext_vector_type(8))) _Float16 h8;
typedef __attribute__((ext_vector_type(4))) float f32x4;
typedef __attribute__((ext_vector_type(4))) unsigned int u4;

extern "C" __device__ __attribute__((const)) float __ocml_native_exp2_f32(float);
#define EXP2F __ocml_native_exp2_f32
#define L2E 1.4426950408889634f

// XOR-swizzle for 128-byte LDS rows (attn kernel).
#define SWZ(row, colByte) \
  (((row) << 7) + ((colByte) ^ (((((row) ^ ((row) >> 3))) & 7) << 4)))

// Async global->LDS, 16 B per lane; LDS dest = wave-uniform base + lane*16.
#define GL16(gp, lp)                                                  \
  __builtin_amdgcn_global_load_lds(                                   \
      (const __attribute__((address_space(1))) unsigned int*)(gp),    \
      (__attribute__((address_space(3))) unsigned int*)(lp), 16, 0, 0)

// ---------------------------------------------------------------------------
// Fused prep (R10-verified): blocks 0-2047 cast hs fp32->f16; blocks
// 2048-5119 transpose the four weight matrices. All outputs LINEAR.
// ---------------------------------------------------------------------------
__global__ __launch_bounds__(256) void prep(
    const float* __restrict__ hs, f16* __restrict__ hsf,
    const float* __restrict__ qw, const float* __restrict__ kw,
    const float* __restrict__ vw, const float* __restrict__ ow,
    f16* __restrict__ wqkv, f16* __restrict__ owt) {
  const int t = threadIdx.x;
  if (blockIdx.x < 2048) {
    const int n4 = 8192 * 1024 / 4;
    for (int i = blockIdx.x * 256 + t; i < n4; i += 2048 * 256) {
      const f4 v = ((const f4*)hs)[i];
      h4 h;
      h.x = (f16)v.x; h.y = (f16)v.y; h.z = (f16)v.z; h.w = (f16)v.w;
      ((h4*)hsf)[i] = h;
    }
    return;
  }
  __shared__ float tile[32][33];
  int bid = blockIdx.x - 2048;
  const float* in;
  f16* out;
  int R, C, bx, by;
  if (bid < 1024) {
    in = qw; out = wqkv; R = 1024; C = 1024; bx = bid & 31; by = bid >> 5;
  } else if (bid < 2048) {
    bid -= 1024;
    in = kw; out = wqkv + (size_t)1024 * 1024; R = 1024; C = 1024;
    bx = bid & 31; by = bid >> 5;
  } else if (bid < 2560) {
    bid -= 2048;
    in = vw; out = wqkv + (size_t)2048 * 1024; R = 1024; C = 512;
    bx = bid & 15; by = bid >> 4;
  } else {
    bid -= 2560;
    in = ow; out = owt; R = 512; C = 1024; bx = bid & 31; by = bid >> 5;
  }
  const int tx = t & 31, ty = t >> 5;
  const int bc = bx * 32, br = by * 32;
#pragma unroll
  for (int i = 0; i < 4; ++i)
    tile[ty + i * 8][tx] = in[(size_t)(br + ty + i * 8) * C + bc + tx];
  __syncthreads();
#pragma unroll
  for (int i = 0; i < 4; ++i)
    out[(size_t)(bc + ty + i * 8) * R + br + tx] = (f16)tile[tx][ty + i * 8];
}

// ---------------------------------------------------------------------------
// Fused QKV projection GEMM (R12-verified core): counted-vmcnt double-buffered
// gload_lds pipeline, BK=32, src-side swizzle. NEW: V-region blocks (bnT>=16)
// transpose their 128(s)x128(nl) output tile via LDS (reusing As after a
// vmcnt(0) drain) and store vfT [bh][r][S] with coalesced 16B runs — the
// separate transpose_v kernel is gone.
// ---------------------------------------------------------------------------
__global__ __launch_bounds__(256) void hgemm_qkv(
    const f16* __restrict__ A, const f16* __restrict__ Bt,
    const float* __restrict__ qb, const float* __restrict__ kb,
    const float* __restrict__ vb,
    f16* __restrict__ qf, f16* __restrict__ kf, f16* __restrict__ vfT) {
  __shared__ f16 As[2 * 128 * 32];
  __shared__ f16 Bs[2 * 128 * 32];
  const int K = 1024;
  const int id = blockIdx.x;
  const int xcd = id & 7, loc = id >> 3;
  const int grp = loc >> 5, inn = loc & 31;
  const int bnT = grp * 4 + (inn >> 3);
  const int bm = (xcd * 8 + (inn & 7)) * 128;
  const int bn = bnT * 128;
  const int t = threadIdx.x;
  const int lane = t & 63, wave = t >> 6;
  const int wr = wave >> 1, wc = wave & 1;
  const int lrow = lane & 15, lk = lane >> 4;
  const int srow = lane >> 2;
  const int sblk = (lane & 3) ^ ((srow ^ (srow >> 2)) & 3);

  f32x4 acc[4][4];
#pragma unroll
  for (int i = 0; i < 4; ++i)
#pragma unroll
    for (int j = 0; j < 4; ++j) acc[i][j] = (f32x4)0.f;

  auto stage = [&](int buf, int ktile) {
#pragma unroll
    for (int i = 0; i < 2; ++i) {
      const int rr = (wave * 2 + i) * 16 + srow;
      GL16(A + (size_t)(bm + rr) * K + ktile * 32 + sblk * 8,
           (char*)As + buf * 8192 + (wave * 2 + i) * 1024);
      GL16(Bt + (size_t)(bn + rr) * K + ktile * 32 + sblk * 8,
           (char*)Bs + buf * 8192 + (wave * 2 + i) * 1024);
    }
  };

  stage(0, 0);
  for (int kt = 0; kt < 32; ++kt) {
    const int cur = kt & 1;
    stage(cur ^ 1, (kt + 1) & 31);
    asm volatile("s_waitcnt vmcnt(4)" ::: "memory");
    __builtin_amdgcn_s_barrier();
    __builtin_amdgcn_sched_barrier(0);
    h8 af[4], bf[4];
#pragma unroll
    for (int f = 0; f < 4; ++f) {
      const int ra = wr * 64 + f * 16 + lrow;
      af[f] = *(const h8*)((char*)As + cur * 8192 + ra * 64 +
                           ((lk ^ ((ra ^ (ra >> 2)) & 3)) << 4));
      const int rb = wc * 64 + f * 16 + lrow;
      bf[f] = *(const h8*)((char*)Bs + cur * 8192 + rb * 64 +
                           ((lk ^ ((rb ^ (rb >> 2)) & 3)) << 4));
    }
#pragma unroll
    for (int i2 = 0; i2 < 4; ++i2)
#pragma unroll
      for (int j = 0; j < 4; ++j)
        acc[i2][j] = __builtin_amdgcn_mfma_f32_16x16x32_f16(af[i2], bf[j], acc[i2][j], 0, 0, 0);
    asm volatile("s_waitcnt lgkmcnt(0)" ::: "memory");
    __builtin_amdgcn_sched_barrier(0);
    __builtin_amdgcn_s_barrier();
  }

  if (bnT < 16) {  // Q/K epilogue (R12-verified, unchanged)
    const float* bias = (bnT < 8) ? qb : kb;
    const int nbase = (bnT < 8) ? 0 : 1024;
    f16* outp = (bnT < 8) ? qf : kf;
#pragma unroll
    for (int fi = 0; fi < 4; ++fi) {
#pragma unroll
      for (int j = 0; j < 4; ++j) {
        const int grow = bm + wr * 64 + fi * 16 + lk * 4 + j;
        const int bb = grow >> 11, ss = grow & 2047;
#pragma unroll
        for (int fj = 0; fj < 4; ++fj) {
          const int gcol = bn + wc * 64 + fj * 16 + lrow;
          const int nl = gcol - nbase;
          const float g = acc[fi][fj][j] + bias[nl];
          outp[((size_t)(bb * 16 + (nl >> 6)) * 2048 + ss) * 64 + (nl & 63)] = (f16)g;
        }
      }
    }
    return;
  }

  // ---- V epilogue: LDS transpose (reuse As), coalesced vfT stores ----
  // Drain the wrap-around prefetch still writing into As/Bs, then reuse As.
  asm volatile("s_waitcnt vmcnt(0)" ::: "memory");
  __syncthreads();
  f16* T = As;                 // scratch: T[64 cols][128 s], s XOR-swizzled
  const int nlq = bn - 2048;   // 0,128,256,384
  const int bb = bm >> 11, sbase = bm & 2047;
#pragma unroll
  for (int hh = 0; hh < 2; ++hh) {
    if (wc == hh) {  // writing waves own cols hh*64..+63
#pragma unroll
      for (int fi = 0; fi < 4; ++fi)
#pragma unroll
        for (int j = 0; j < 4; ++j) {
          const int sp = wr * 64 + fi * 16 + lk * 4 + j;  // local s 0..127
#pragma unroll
          for (int fj = 0; fj < 4; ++fj) {
            const int c = fj * 16 + lrow;  // local col 0..63
            const int nl = nlq + hh * 64 + c;
            T[c * 128 + (sp ^ ((c & 7) << 4))] = (f16)(acc[fi][fj][j] + vb[nl]);
          }
        }
    }
    __syncthreads();
    {  // all threads: coalesced read + 16B global stores
      const int c = t >> 2;
      const int nl = nlq + hh * 64 + c;
      f16* dst = vfT + ((size_t)(bb * 16 + (nl >> 5)) * 32 + (nl & 31)) * 2048 + sbase;
      const int s0b = (t & 3) * 32;
#pragma unroll
      for (int i2 = 0; i2 < 4; ++i2) {
        const int s0 = s0b + i2 * 8;
        const h8 v = *(const h8*)&T[c * 128 + (s0 ^ ((c & 7) << 4))];
        *(u4*)(dst + s0) = __builtin_bit_cast(u4, v);
      }
    }
    __syncthreads();
  }
}

// ---------------------------------------------------------------------------
// Output projection GEMM (R4-verified, unchanged).
// ---------------------------------------------------------------------------
__global__ __launch_bounds__(256) void hgemm_out(
    const f16* __restrict__ A, const f16* __restrict__ Bt,
    const float* __restrict__ bias, float* __restrict__ outp,
    const int N, const int K) {
  __shared__ f16 As[128 * 40];
  __shared__ f16 Bs[128 * 40];
  const int id = blockIdx.x;
  const int swz = (id & 7) * 64 + (id >> 3);
  const int bn = (swz & 7) * 128;
  const int bm = (swz >> 3) * 128;
  const int t = threadIdx.x;
  const int lane = t & 63, wave = t >> 6;
  const int wr = wave >> 1, wc = wave & 1;
  const int lrow = lane & 15, lk = lane >> 4;

  f32x4 acc[4][4];
#pragma unroll
  for (int i = 0; i < 4; ++i)
#pragma unroll
    for (int j = 0; j < 4; ++j) acc[i][j] = (f32x4)0.f;

  for (int kt = 0; kt < K; kt += 32) {
#pragma unroll
    for (int i = 0; i < 2; ++i) {
      const int ch = t + i * 256;
      const int row = ch >> 2, part = ch & 3;
      *(u4*)&As[row * 40 + part * 8] =
          *(const u4*)(A + (size_t)(bm + row) * K + kt + part * 8);
      *(u4*)&Bs[row * 40 + part * 8] =
          *(const u4*)(Bt + (size_t)(bn + row) * K + kt + part * 8);
    }
    __syncthreads();
    h8 af[4], bf[4];
#pragma unroll
    for (int f = 0; f < 4; ++f) {
      af[f] = *(const h8*)&As[(wr * 64 + f * 16 + lrow) * 40 + lk * 8];
      bf[f] = *(const h8*)&Bs[(wc * 64 + f * 16 + lrow) * 40 + lk * 8];
    }
#pragma unroll
    for (int i = 0; i < 4; ++i)
#pragma unroll
      for (int j = 0; j < 4; ++j)
        acc[i][j] = __builtin_amdgcn_mfma_f32_16x16x32_f16(af[i], bf[j], acc[i][j], 0, 0, 0);
    __syncthreads();
  }

#pragma unroll
  for (int fi = 0; fi < 4; ++fi) {
#pragma unroll
    for (int j = 0; j < 4; ++j) {
      const int grow = bm + wr * 64 + fi * 16 + lk * 4 + j;
#pragma unroll
      for (int fj = 0; fj < 4; ++fj) {
        const int gcol = bn + wc * 64 + fj * 16 + lrow;
        outp[(size_t)grow * N + gcol] = acc[fi][fj][j] + bias[gcol];
      }
    }
  }
}

// ---------------------------------------------------------------------------
// MFMA causal flash attention (R12/R17-verified, unchanged: setprio + THR=8
// were neutral; kept).
// qf/kf: [64][2048][64] f16; vfT: [64][32][2048] f16; attf: [8192][512] f16.
// ---------------------------------------------------------------------------
__global__ __launch_bounds__(256) void attn_mfma(
    const f16* __restrict__ qf, const f16* __restrict__ kf,
    const f16* __restrict__ vfT, f16* __restrict__ attf) {
  __shared__ f16 Ks[64 * 64];
  __shared__ f16 VsT[32 * 64];
  __shared__ f16 Ps[4 * 32 * 64];
  const int id = blockIdx.x;
  const int bh = id & 63;
  const int qblk = 15 - (id >> 6);
  const int qbase = qblk * 128;
  const int t = threadIdx.x;
  const int lane = t & 63, w = t >> 6;
  const int l15 = lane & 15, g = lane >> 4;
  const size_t kvbase = (size_t)bh * 2048;
  char* Pw = (char*)&Ps[w * 32 * 64];

  h8 ones;
#pragma unroll
  for (int e = 0; e < 8; ++e) ones[e] = (f16)1.0f;

  h8 qreg[2][2];
#pragma unroll
  for (int fj = 0; fj < 2; ++fj) {
    const int q = qbase + fj * 64 + w * 16 + l15;
#pragma unroll
    for (int ks = 0; ks < 2; ++ks) {
      h8 raw = *(const h8*)(qf + (kvbase + q) * 64 + ks * 32 + g * 8);
#pragma unroll
      for (int e = 0; e < 8; ++e) raw[e] = raw[e] * (f16)0.125f;
      qreg[fj][ks] = raw;
    }
  }

  f32x4 accO[2][2];
  f32x4 accL[2];
#pragma unroll
  for (int i = 0; i < 2; ++i) {
    accL[i] = (f32x4)0.f;
#pragma unroll
    for (int j = 0; j < 2; ++j) accO[i][j] = (f32x4)0.f;
  }
  float m2[2] = {-1.0e30f, -1.0e30f};

  const int ntiles = qblk * 2 + 2;
  for (int kt = 0; kt < ntiles; ++kt) {
    const int kbase = kt * 64;
    __syncthreads();
#pragma unroll
    for (int i = 0; i < 2; ++i) {
      const int idx = t + i * 256;
      const int row = idx >> 3, ch = idx & 7;
      *(u4*)((char*)Ks + SWZ(row, ch * 16)) =
          *(const u4*)(kf + (kvbase + kbase + row) * 64 + ch * 8);
    }
    {
      const int row = t >> 3, ch = t & 7;
      *(u4*)((char*)VsT + SWZ(row, ch * 16)) =
          *(const u4*)(vfT + ((size_t)bh * 32 + row) * 2048 + kbase + ch * 8);
    }
    __syncthreads();

    f32x4 accS[4][2];
#pragma unroll
    for (int i = 0; i < 4; ++i)
#pragma unroll
      for (int j = 0; j < 2; ++j) accS[i][j] = (f32x4)0.f;
    __builtin_amdgcn_s_setprio(1);
#pragma unroll
    for (int ks = 0; ks < 2; ++ks) {
#pragma unroll
      for (int fim = 0; fim < 4; ++fim) {
        const h8 af = *(const h8*)((char*)Ks + SWZ(fim * 16 + l15, ks * 64 + g * 16));
#pragma unroll
        for (int fj = 0; fj < 2; ++fj)
          accS[fim][fj] = __builtin_amdgcn_mfma_f32_16x16x32_f16(af, qreg[fj][ks], accS[fim][fj], 0, 0, 0);
      }
    }
    __builtin_amdgcn_s_setprio(0);

#pragma unroll
    for (int fj = 0; fj < 2; ++fj) {
      const int qg = qbase + fj * 64 + w * 16 + l15;
      const bool need_mask = (kbase + 63 > qbase + fj * 64 + w * 16);
      float sc[4][4];
#pragma unroll
      for (int fim = 0; fim < 4; ++fim)
#pragma unroll
        for (int j = 0; j < 4; ++j) {
          float v = accS[fim][fj][j];
          if (need_mask) {
            const int key = kbase + fim * 16 + g * 4 + j;
            v = (key <= qg) ? v : -1.0e30f;
          }
          sc[fim][j] = v;
        }
      const float a0 = fmaxf(fmaxf(sc[0][0], sc[0][1]), sc[0][2]);
      const float a1 = fmaxf(fmaxf(sc[0][3], sc[1][0]), sc[1][1]);
      const float a2 = fmaxf(fmaxf(sc[1][2], sc[1][3]), sc[2][0]);
      const float a3 = fmaxf(fmaxf(sc[2][1], sc[2][2]), sc[2][3]);
      const float a4 = fmaxf(fmaxf(sc[3][0], sc[3][1]), sc[3][2]);
      float mc = fmaxf(fmaxf(fmaxf(a0, a1), a2),
                       fmaxf(fmaxf(a3, a4), sc[3][3]));
      mc = fmaxf(mc, __shfl_xor(mc, 16));
      mc = fmaxf(mc, __shfl_xor(mc, 32));
      if (!__all(mc <= m2[fj] + 8.0f)) {
        const float mnew = fmaxf(m2[fj], mc);
        const float corr = __expf(m2[fj] - mnew);
        m2[fj] = mnew;
#pragma unroll
        for (int j = 0; j < 4; ++j) {
          const float c = __shfl(corr, g * 4 + j);
          accO[fj][0][j] *= c;
          accO[fj][1][j] *= c;
          accL[fj][j] *= c;
        }
      }
      const float nml = -m2[fj] * L2E;
#pragma unroll
      for (int fim = 0; fim < 4; ++fim) {
        h4 hp;
#pragma unroll
        for (int j = 0; j < 4; ++j)
          hp[j] = (f16)EXP2F(fmaf(sc[fim][j], L2E, nml));
        *(h4*)(Pw + SWZ(fj * 16 + l15, fim * 32 + g * 8)) = hp;
      }
    }

    __builtin_amdgcn_s_setprio(1);
#pragma unroll
    for (int ks = 0; ks < 2; ++ks) {
      const h8 pa0 = *(const h8*)(Pw + SWZ(l15, ks * 64 + g * 16));
      const h8 pa1 = *(const h8*)(Pw + SWZ(16 + l15, ks * 64 + g * 16));
#pragma unroll
      for (int fr = 0; fr < 2; ++fr) {
        const h8 vb = *(const h8*)((char*)VsT + SWZ(fr * 16 + l15, ks * 64 + g * 16));
        accO[0][fr] = __builtin_amdgcn_mfma_f32_16x16x32_f16(pa0, vb, accO[0][fr], 0, 0, 0);
        accO[1][fr] = __builtin_amdgcn_mfma_f32_16x16x32_f16(pa1, vb, accO[1][fr], 0, 0, 0);
      }
      accL[0] = __builtin_amdgcn_mfma_f32_16x16x32_f16(pa0, ones, accL[0], 0, 0, 0);
      accL[1] = __builtin_amdgcn_mfma_f32_16x16x32_f16(pa1, ones, accL[1], 0, 0, 0);
    }
    __builtin_amdgcn_s_setprio(0);
  }

  const int b = bh >> 4, h = bh & 15;
#pragma unroll
  for (int fo = 0; fo < 2; ++fo) {
#pragma unroll
    for (int j = 0; j < 4; ++j) {
      const float iv = 1.f / accL[fo][j];
      const int q = qbase + fo * 64 + w * 16 + g * 4 + j;
#pragma unroll
      for (int fr = 0; fr < 2; ++fr) {
        const int r = fr * 16 + l15;
        attf[((size_t)b * 2048 + q) * 512 + h * 32 + r] = (f16)(accO[fo][fr][j] * iv);
      }
    }
  }
}

// ---------------------------------------------------------------------------
extern "C" void kernel_launch(void* const* d_in, const int* in_sizes, int n_in,
                              void* d_out, int out_size, void* d_ws, size_t ws_size,
                              hipStream_t stream) {
  const float* hs = (const float*)d_in[0];
  const float* qw = (const float*)d_in[1];
  const float* qb = (const float*)d_in[2];
  const float* kw = (const float*)d_in[3];
  const float* kb = (const float*)d_in[4];
  const float* vw = (const float*)d_in[5];
  const float* vb = (const float*)d_in[6];
  const float* ow = (const float*)d_in[7];
  const float* ob = (const float*)d_in[8];
  float* out = (float*)d_out;
  char* ws = (char*)d_ws;

  // Scratch (MB offsets), 80 MB total (ws >= 96 MB proven in R3):
  f16* qf = (f16*)(ws);                         // 16 MB [64][2048][64]
  f16* kf = (f16*)(ws + ((size_t)16 << 20));    // 16 MB
  f16* vfT = (f16*)(ws + ((size_t)72 << 20));   //  8 MB [64][32][2048]
  f16* attf = (f16*)(ws + ((size_t)40 << 20));  //  8 MB [8192][512]
  f16* wqkv = (f16*)(ws + ((size_t)48 << 20));  //  5 MB [2560][1024]
  f16* owt = (f16*)(ws + ((size_t)53 << 20));   //  1 MB [1024][512]
  f16* hsf = (f16*)(ws + ((size_t)56 << 20));   // 16 MB [8192][1024]

  prep<<<dim3(5120), 256, 0, stream>>>(hs, hsf, qw, kw, vw, ow, wqkv, owt);
  hgemm_qkv<<<dim3(1280), 256, 0, stream>>>(hsf, wqkv, qb, kb, vb, qf, kf, vfT);
  attn_mfma<<<dim3(1024), 256, 0, stream>>>(qf, kf, vfT, attf);
  hgemm_out<<<dim3(512), 256, 0, stream>>>(attf, owt, ob, out, 1024, 512);
}

// Round 19
// 162.781 us; speedup vs baseline: 1.0597x; 1.0597x over previous
//
#include <hip/hip_runtime.h>

typedef _Float16 f16;
typedef __attribute__((ext_vector_type(4))) float f4;
typedef __attribute__((ext_vector_type(4))) _Float16 h4;
typedef __attribute__((ext_vector_type(8))) _Float16 h8;
typedef __attribute__((ext_vector_type(4))) float f32x4;
typedef __attribute__((ext_vector_type(4))) unsigned int u4;

extern "C" __device__ __attribute__((const)) float __ocml_native_exp2_f32(float);
#define EXP2F __ocml_native_exp2_f32
#define L2E 1.4426950408889634f

// XOR-swizzle for 128-byte LDS rows (attn kernel).
#define SWZ(row, colByte) \
  (((row) << 7) + ((colByte) ^ (((((row) ^ ((row) >> 3))) & 7) << 4)))

// Async global->LDS, 16 B per lane; LDS dest = wave-uniform base + lane*16.
#define GL16(gp, lp)                                                  \
  __builtin_amdgcn_global_load_lds(                                   \
      (const __attribute__((address_space(1))) unsigned int*)(gp),    \
      (__attribute__((address_space(3))) unsigned int*)(lp), 16, 0, 0)

// ---------------------------------------------------------------------------
// Fused prep (R10-verified): blocks 0-2047 cast hs fp32->f16; blocks
// 2048-5119 transpose the four weight matrices. All outputs LINEAR.
// ---------------------------------------------------------------------------
__global__ __launch_bounds__(256) void prep(
    const float* __restrict__ hs, f16* __restrict__ hsf,
    const float* __restrict__ qw, const float* __restrict__ kw,
    const float* __restrict__ vw, const float* __restrict__ ow,
    f16* __restrict__ wqkv, f16* __restrict__ owt) {
  const int t = threadIdx.x;
  if (blockIdx.x < 2048) {
    const int n4 = 8192 * 1024 / 4;
    for (int i = blockIdx.x * 256 + t; i < n4; i += 2048 * 256) {
      const f4 v = ((const f4*)hs)[i];
      h4 h;
      h.x = (f16)v.x; h.y = (f16)v.y; h.z = (f16)v.z; h.w = (f16)v.w;
      ((h4*)hsf)[i] = h;
    }
    return;
  }
  __shared__ float tile[32][33];
  int bid = blockIdx.x - 2048;
  const float* in;
  f16* out;
  int R, C, bx, by;
  if (bid < 1024) {
    in = qw; out = wqkv; R = 1024; C = 1024; bx = bid & 31; by = bid >> 5;
  } else if (bid < 2048) {
    bid -= 1024;
    in = kw; out = wqkv + (size_t)1024 * 1024; R = 1024; C = 1024;
    bx = bid & 31; by = bid >> 5;
  } else if (bid < 2560) {
    bid -= 2048;
    in = vw; out = wqkv + (size_t)2048 * 1024; R = 1024; C = 512;
    bx = bid & 15; by = bid >> 4;
  } else {
    bid -= 2560;
    in = ow; out = owt; R = 512; C = 1024; bx = bid & 31; by = bid >> 5;
  }
  const int tx = t & 31, ty = t >> 5;
  const int bc = bx * 32, br = by * 32;
#pragma unroll
  for (int i = 0; i < 4; ++i)
    tile[ty + i * 8][tx] = in[(size_t)(br + ty + i * 8) * C + bc + tx];
  __syncthreads();
#pragma unroll
  for (int i = 0; i < 4; ++i)
    out[(size_t)(bc + ty + i * 8) * R + br + tx] = (f16)tile[tx][ty + i * 8];
}

// ---------------------------------------------------------------------------
// Fused QKV projection GEMM (R12-verified): counted-vmcnt double-buffered
// gload_lds pipeline, BK=32, source-side swizzle, XCD-chunked block order.
// ---------------------------------------------------------------------------
__global__ __launch_bounds__(256) void hgemm_qkv(
    const f16* __restrict__ A, const f16* __restrict__ Bt,
    const float* __restrict__ qb, const float* __restrict__ kb,
    const float* __restrict__ vb,
    f16* __restrict__ qf, f16* __restrict__ kf, f16* __restrict__ vf) {
  __shared__ f16 As[2 * 128 * 32];
  __shared__ f16 Bs[2 * 128 * 32];
  const int K = 1024;
  const int id = blockIdx.x;
  const int xcd = id & 7, loc = id >> 3;
  const int grp = loc >> 5, inn = loc & 31;
  const int bnT = grp * 4 + (inn >> 3);
  const int bm = (xcd * 8 + (inn & 7)) * 128;
  const int bn = bnT * 128;
  const int t = threadIdx.x;
  const int lane = t & 63, wave = t >> 6;
  const int wr = wave >> 1, wc = wave & 1;
  const int lrow = lane & 15, lk = lane >> 4;
  const int srow = lane >> 2;
  const int sblk = (lane & 3) ^ ((srow ^ (srow >> 2)) & 3);

  f32x4 acc[4][4];
#pragma unroll
  for (int i = 0; i < 4; ++i)
#pragma unroll
    for (int j = 0; j < 4; ++j) acc[i][j] = (f32x4)0.f;

  auto stage = [&](int buf, int ktile) {
#pragma unroll
    for (int i = 0; i < 2; ++i) {
      const int rr = (wave * 2 + i) * 16 + srow;
      GL16(A + (size_t)(bm + rr) * K + ktile * 32 + sblk * 8,
           (char*)As + buf * 8192 + (wave * 2 + i) * 1024);
      GL16(Bt + (size_t)(bn + rr) * K + ktile * 32 + sblk * 8,
           (char*)Bs + buf * 8192 + (wave * 2 + i) * 1024);
    }
  };

  stage(0, 0);
  for (int kt = 0; kt < 32; ++kt) {
    const int cur = kt & 1;
    stage(cur ^ 1, (kt + 1) & 31);
    asm volatile("s_waitcnt vmcnt(4)" ::: "memory");
    __builtin_amdgcn_s_barrier();
    __builtin_amdgcn_sched_barrier(0);
    h8 af[4], bf[4];
#pragma unroll
    for (int f = 0; f < 4; ++f) {
      const int ra = wr * 64 + f * 16 + lrow;
      af[f] = *(const h8*)((char*)As + cur * 8192 + ra * 64 +
                           ((lk ^ ((ra ^ (ra >> 2)) & 3)) << 4));
      const int rb = wc * 64 + f * 16 + lrow;
      bf[f] = *(const h8*)((char*)Bs + cur * 8192 + rb * 64 +
                           ((lk ^ ((rb ^ (rb >> 2)) & 3)) << 4));
    }
#pragma unroll
    for (int i2 = 0; i2 < 4; ++i2)
#pragma unroll
      for (int j = 0; j < 4; ++j)
        acc[i2][j] = __builtin_amdgcn_mfma_f32_16x16x32_f16(af[i2], bf[j], acc[i2][j], 0, 0, 0);
    asm volatile("s_waitcnt lgkmcnt(0)" ::: "memory");
    __builtin_amdgcn_sched_barrier(0);
    __builtin_amdgcn_s_barrier();
  }

  const float* bias;
  int nbase;
  if (bnT < 8) { bias = qb; nbase = 0; }
  else if (bnT < 16) { bias = kb; nbase = 1024; }
  else { bias = vb; nbase = 2048; }

#pragma unroll
  for (int fi = 0; fi < 4; ++fi) {
#pragma unroll
    for (int j = 0; j < 4; ++j) {
      const int grow = bm + wr * 64 + fi * 16 + lk * 4 + j;
      const int bb = grow >> 11, ss = grow & 2047;
#pragma unroll
      for (int fj = 0; fj < 4; ++fj) {
        const int gcol = bn + wc * 64 + fj * 16 + lrow;
        const int nl = gcol - nbase;
        const float g = acc[fi][fj][j] + bias[nl];
        if (bnT < 8) {
          qf[((size_t)(bb * 16 + (nl >> 6)) * 2048 + ss) * 64 + (nl & 63)] = (f16)g;
        } else if (bnT < 16) {
          kf[((size_t)(bb * 16 + (nl >> 6)) * 2048 + ss) * 64 + (nl & 63)] = (f16)g;
        } else {
          vf[((size_t)(bb * 16 + (nl >> 5)) * 2048 + ss) * 32 + (nl & 31)] = (f16)g;
        }
      }
    }
  }
}

// ---------------------------------------------------------------------------
// V transpose (R10-verified): vf [64][2048][32] -> vfT [64][32][2048].
// ---------------------------------------------------------------------------
__global__ __launch_bounds__(256) void transpose_v(
    const f16* __restrict__ vf, f16* __restrict__ vfT) {
  __shared__ f16 tl[32][36];
  const int bh = blockIdx.x >> 6;
  const int st = (blockIdx.x & 63) * 32;
  const int t = threadIdx.x;
  const int row = t >> 3, cq = t & 7;
  {
    const h4 v = *(const h4*)(vf + ((size_t)bh * 2048 + st + row) * 32 + cq * 4);
    *(h4*)&tl[row][cq * 4] = v;
  }
  __syncthreads();
  {
    h4 v;
#pragma unroll
    for (int e = 0; e < 4; ++e) v[e] = tl[cq * 4 + e][row];
    *(h4*)(vfT + ((size_t)bh * 32 + row) * 2048 + st + cq * 4) = v;
  }
}

// ---------------------------------------------------------------------------
// Output projection GEMM (R4-verified): out = attf @ owt^T + ob. fp32 out.
// ---------------------------------------------------------------------------
__global__ __launch_bounds__(256) void hgemm_out(
    const f16* __restrict__ A, const f16* __restrict__ Bt,
    const float* __restrict__ bias, float* __restrict__ outp,
    const int N, const int K) {
  __shared__ f16 As[128 * 40];
  __shared__ f16 Bs[128 * 40];
  const int id = blockIdx.x;
  const int swz = (id & 7) * 64 + (id >> 3);
  const int bn = (swz & 7) * 128;
  const int bm = (swz >> 3) * 128;
  const int t = threadIdx.x;
  const int lane = t & 63, wave = t >> 6;
  const int wr = wave >> 1, wc = wave & 1;
  const int lrow = lane & 15, lk = lane >> 4;

  f32x4 acc[4][4];
#pragma unroll
  for (int i = 0; i < 4; ++i)
#pragma unroll
    for (int j = 0; j < 4; ++j) acc[i][j] = (f32x4)0.f;

  for (int kt = 0; kt < K; kt += 32) {
#pragma unroll
    for (int i = 0; i < 2; ++i) {
      const int ch = t + i * 256;
      const int row = ch >> 2, part = ch & 3;
      *(u4*)&As[row * 40 + part * 8] =
          *(const u4*)(A + (size_t)(bm + row) * K + kt + part * 8);
      *(u4*)&Bs[row * 40 + part * 8] =
          *(const u4*)(Bt + (size_t)(bn + row) * K + kt + part * 8);
    }
    __syncthreads();
    h8 af[4], bf[4];
#pragma unroll
    for (int f = 0; f < 4; ++f) {
      af[f] = *(const h8*)&As[(wr * 64 + f * 16 + lrow) * 40 + lk * 8];
      bf[f] = *(const h8*)&Bs[(wc * 64 + f * 16 + lrow) * 40 + lk * 8];
    }
#pragma unroll
    for (int i = 0; i < 4; ++i)
#pragma unroll
      for (int j = 0; j < 4; ++j)
        acc[i][j] = __builtin_amdgcn_mfma_f32_16x16x32_f16(af[i], bf[j], acc[i][j], 0, 0, 0);
    __syncthreads();
  }

#pragma unroll
  for (int fi = 0; fi < 4; ++fi) {
#pragma unroll
    for (int j = 0; j < 4; ++j) {
      const int grow = bm + wr * 64 + fi * 16 + lk * 4 + j;
#pragma unroll
      for (int fj = 0; fj < 4; ++fj) {
        const int gcol = bn + wc * 64 + fj * 16 + lrow;
        outp[(size_t)grow * N + gcol] = acc[fi][fj][j] + bias[gcol];
      }
    }
  }
}

// ---------------------------------------------------------------------------
// MFMA causal flash attention (R12-verified best).
// qf/kf: [64][2048][64] f16; vfT: [64][32][2048] f16; attf: [8192][512] f16.
// ---------------------------------------------------------------------------
__global__ __launch_bounds__(256) void attn_mfma(
    const f16* __restrict__ qf, const f16* __restrict__ kf,
    const f16* __restrict__ vfT, f16* __restrict__ attf) {
  __shared__ f16 Ks[64 * 64];
  __shared__ f16 VsT[32 * 64];
  __shared__ f16 Ps[4 * 32 * 64];
  const int id = blockIdx.x;
  const int bh = id & 63;
  const int qblk = 15 - (id >> 6);
  const int qbase = qblk * 128;
  const int t = threadIdx.x;
  const int lane = t & 63, w = t >> 6;
  const int l15 = lane & 15, g = lane >> 4;
  const size_t kvbase = (size_t)bh * 2048;
  char* Pw = (char*)&Ps[w * 32 * 64];

  h8 ones;
#pragma unroll
  for (int e = 0; e < 8; ++e) ones[e] = (f16)1.0f;

  h8 qreg[2][2];
#pragma unroll
  for (int fj = 0; fj < 2; ++fj) {
    const int q = qbase + fj * 64 + w * 16 + l15;
#pragma unroll
    for (int ks = 0; ks < 2; ++ks) {
      h8 raw = *(const h8*)(qf + (kvbase + q) * 64 + ks * 32 + g * 8);
#pragma unroll
      for (int e = 0; e < 8; ++e) raw[e] = raw[e] * (f16)0.125f;
      qreg[fj][ks] = raw;
    }
  }

  f32x4 accO[2][2];
  f32x4 accL[2];
#pragma unroll
  for (int i = 0; i < 2; ++i) {
    accL[i] = (f32x4)0.f;
#pragma unroll
    for (int j = 0; j < 2; ++j) accO[i][j] = (f32x4)0.f;
  }
  float m2[2] = {-1.0e30f, -1.0e30f};

  const int ntiles = qblk * 2 + 2;
  for (int kt = 0; kt < ntiles; ++kt) {
    const int kbase = kt * 64;
    __syncthreads();
#pragma unroll
    for (int i = 0; i < 2; ++i) {
      const int idx = t + i * 256;
      const int row = idx >> 3, ch = idx & 7;
      *(u4*)((char*)Ks + SWZ(row, ch * 16)) =
          *(const u4*)(kf + (kvbase + kbase + row) * 64 + ch * 8);
    }
    {
      const int row = t >> 3, ch = t & 7;
      *(u4*)((char*)VsT + SWZ(row, ch * 16)) =
          *(const u4*)(vfT + ((size_t)bh * 32 + row) * 2048 + kbase + ch * 8);
    }
    __syncthreads();

    f32x4 accS[4][2];
#pragma unroll
    for (int i = 0; i < 4; ++i)
#pragma unroll
      for (int j = 0; j < 2; ++j) accS[i][j] = (f32x4)0.f;
#pragma unroll
    for (int ks = 0; ks < 2; ++ks) {
#pragma unroll
      for (int fim = 0; fim < 4; ++fim) {
        const h8 af = *(const h8*)((char*)Ks + SWZ(fim * 16 + l15, ks * 64 + g * 16));
#pragma unroll
        for (int fj = 0; fj < 2; ++fj)
          accS[fim][fj] = __builtin_amdgcn_mfma_f32_16x16x32_f16(af, qreg[fj][ks], accS[fim][fj], 0, 0, 0);
      }
    }

#pragma unroll
    for (int fj = 0; fj < 2; ++fj) {
      const int qg = qbase + fj * 64 + w * 16 + l15;
      const bool need_mask = (kbase + 63 > qbase + fj * 64 + w * 16);
      float sc[4][4];
#pragma unroll
      for (int fim = 0; fim < 4; ++fim)
#pragma unroll
        for (int j = 0; j < 4; ++j) {
          float v = accS[fim][fj][j];
          if (need_mask) {
            const int key = kbase + fim * 16 + g * 4 + j;
            v = (key <= qg) ? v : -1.0e30f;
          }
          sc[fim][j] = v;
        }
      const float a0 = fmaxf(fmaxf(sc[0][0], sc[0][1]), sc[0][2]);
      const float a1 = fmaxf(fmaxf(sc[0][3], sc[1][0]), sc[1][1]);
      const float a2 = fmaxf(fmaxf(sc[1][2], sc[1][3]), sc[2][0]);
      const float a3 = fmaxf(fmaxf(sc[2][1], sc[2][2]), sc[2][3]);
      const float a4 = fmaxf(fmaxf(sc[3][0], sc[3][1]), sc[3][2]);
      float mc = fmaxf(fmaxf(fmaxf(a0, a1), a2),
                       fmaxf(fmaxf(a3, a4), sc[3][3]));
      mc = fmaxf(mc, __shfl_xor(mc, 16));
      mc = fmaxf(mc, __shfl_xor(mc, 32));
      if (!__all(mc <= m2[fj] + 1.5f)) {
        const float mnew = fmaxf(m2[fj], mc);
        const float corr = __expf(m2[fj] - mnew);
        m2[fj] = mnew;
#pragma unroll
        for (int j = 0; j < 4; ++j) {
          const float c = __shfl(corr, g * 4 + j);
          accO[fj][0][j] *= c;
          accO[fj][1][j] *= c;
          accL[fj][j] *= c;
        }
      }
      const float nml = -m2[fj] * L2E;
#pragma unroll
      for (int fim = 0; fim < 4; ++fim) {
        h4 hp;
#pragma unroll
        for (int j = 0; j < 4; ++j)
          hp[j] = (f16)EXP2F(fmaf(sc[fim][j], L2E, nml));
        *(h4*)(Pw + SWZ(fj * 16 + l15, fim * 32 + g * 8)) = hp;
      }
    }

#pragma unroll
    for (int ks = 0; ks < 2; ++ks) {
      const h8 pa0 = *(const h8*)(Pw + SWZ(l15, ks * 64 + g * 16));
      const h8 pa1 = *(const h8*)(Pw + SWZ(16 + l15, ks * 64 + g * 16));
#pragma unroll
      for (int fr = 0; fr < 2; ++fr) {
        const h8 vb = *(const h8*)((char*)VsT + SWZ(fr * 16 + l15, ks * 64 + g * 16));
        accO[0][fr] = __builtin_amdgcn_mfma_f32_16x16x32_f16(pa0, vb, accO[0][fr], 0, 0, 0);
        accO[1][fr] = __builtin_amdgcn_mfma_f32_16x16x32_f16(pa1, vb, accO[1][fr], 0, 0, 0);
      }
      accL[0] = __builtin_amdgcn_mfma_f32_16x16x32_f16(pa0, ones, accL[0], 0, 0, 0);
      accL[1] = __builtin_amdgcn_mfma_f32_16x16x32_f16(pa1, ones, accL[1], 0, 0, 0);
    }
  }

  const int b = bh >> 4, h = bh & 15;
#pragma unroll
  for (int fo = 0; fo < 2; ++fo) {
#pragma unroll
    for (int j = 0; j < 4; ++j) {
      const float iv = 1.f / accL[fo][j];
      const int q = qbase + fo * 64 + w * 16 + g * 4 + j;
#pragma unroll
      for (int fr = 0; fr < 2; ++fr) {
        const int r = fr * 16 + l15;
        attf[((size_t)b * 2048 + q) * 512 + h * 32 + r] = (f16)(accO[fo][fr][j] * iv);
      }
    }
  }
}

// ---------------------------------------------------------------------------
extern "C" void kernel_launch(void* const* d_in, const int* in_sizes, int n_in,
                              void* d_out, int out_size, void* d_ws, size_t ws_size,
                              hipStream_t stream) {
  const float* hs = (const float*)d_in[0];
  const float* qw = (const float*)d_in[1];
  const float* qb = (const float*)d_in[2];
  const float* kw = (const float*)d_in[3];
  const float* kb = (const float*)d_in[4];
  const float* vw = (const float*)d_in[5];
  const float* vb = (const float*)d_in[6];
  const float* ow = (const float*)d_in[7];
  const float* ob = (const float*)d_in[8];
  float* out = (float*)d_out;
  char* ws = (char*)d_ws;

  // Scratch (MB offsets), 80 MB total (ws >= 96 MB proven in R3):
  f16* qf = (f16*)(ws);                         // 16 MB [64][2048][64]
  f16* kf = (f16*)(ws + ((size_t)16 << 20));    // 16 MB
  f16* vf = (f16*)(ws + ((size_t)32 << 20));    //  8 MB [64][2048][32]
  f16* vfT = (f16*)(ws + ((size_t)72 << 20));   //  8 MB [64][32][2048]
  f16* attf = (f16*)(ws + ((size_t)40 << 20));  //  8 MB [8192][512]
  f16* wqkv = (f16*)(ws + ((size_t)48 << 20));  //  5 MB [2560][1024]
  f16* owt = (f16*)(ws + ((size_t)53 << 20));   //  1 MB [1024][512]
  f16* hsf = (f16*)(ws + ((size_t)56 << 20));   // 16 MB [8192][1024]

  prep<<<dim3(5120), 256, 0, stream>>>(hs, hsf, qw, kw, vw, ow, wqkv, owt);
  hgemm_qkv<<<dim3(1280), 256, 0, stream>>>(hsf, wqkv, qb, kb, vb, qf, kf, vf);
  transpose_v<<<dim3(4096), 256, 0, stream>>>(vf, vfT);
  attn_mfma<<<dim3(1024), 256, 0, stream>>>(qf, kf, vfT, attf);
  hgemm_out<<<dim3(512), 256, 0, stream>>>(attf, owt, ob, out, 1024, 512);
}

// Round 20
// 161.920 us; speedup vs baseline: 1.0653x; 1.0053x over previous
//
#include <hip/hip_runtime.h>

typedef _Float16 f16;
typedef __attribute__((ext_vector_type(4))) float f4;
typedef __attribute__((ext_vector_type(4))) _Float16 h4;
typedef __attribute__((ext_vector_type(8))) _Float16 h8;
typedef __attribute__((ext_vector_type(4))) float f32x4;
typedef __attribute__((ext_vector_type(4))) unsigned int u4;

extern "C" __device__ __attribute__((const)) float __ocml_native_exp2_f32(float);
#define EXP2F __ocml_native_exp2_f32
#define L2E 1.4426950408889634f

// XOR-swizzle for 128-byte LDS rows (attn kernel).
#define SWZ(row, colByte) \
  (((row) << 7) + ((colByte) ^ (((((row) ^ ((row) >> 3))) & 7) << 4)))

// Async global->LDS, 16 B per lane; LDS dest = wave-uniform base + lane*16.
#define GL16(gp, lp)                                                  \
  __builtin_amdgcn_global_load_lds(                                   \
      (const __attribute__((address_space(1))) unsigned int*)(gp),    \
      (__attribute__((address_space(3))) unsigned int*)(lp), 16, 0, 0)

// ---------------------------------------------------------------------------
// Fused prep (R10-verified): blocks 0-2047 cast hs fp32->f16; blocks
// 2048-5119 transpose the four weight matrices. All outputs LINEAR.
// ---------------------------------------------------------------------------
__global__ __launch_bounds__(256) void prep(
    const float* __restrict__ hs, f16* __restrict__ hsf,
    const float* __restrict__ qw, const float* __restrict__ kw,
    const float* __restrict__ vw, const float* __restrict__ ow,
    f16* __restrict__ wqkv, f16* __restrict__ owt) {
  const int t = threadIdx.x;
  if (blockIdx.x < 2048) {
    const int n4 = 8192 * 1024 / 4;
    for (int i = blockIdx.x * 256 + t; i < n4; i += 2048 * 256) {
      const f4 v = ((const f4*)hs)[i];
      h4 h;
      h.x = (f16)v.x; h.y = (f16)v.y; h.z = (f16)v.z; h.w = (f16)v.w;
      ((h4*)hsf)[i] = h;
    }
    return;
  }
  __shared__ float tile[32][33];
  int bid = blockIdx.x - 2048;
  const float* in;
  f16* out;
  int R, C, bx, by;
  if (bid < 1024) {
    in = qw; out = wqkv; R = 1024; C = 1024; bx = bid & 31; by = bid >> 5;
  } else if (bid < 2048) {
    bid -= 1024;
    in = kw; out = wqkv + (size_t)1024 * 1024; R = 1024; C = 1024;
    bx = bid & 31; by = bid >> 5;
  } else if (bid < 2560) {
    bid -= 2048;
    in = vw; out = wqkv + (size_t)2048 * 1024; R = 1024; C = 512;
    bx = bid & 15; by = bid >> 4;
  } else {
    bid -= 2560;
    in = ow; out = owt; R = 512; C = 1024; bx = bid & 31; by = bid >> 5;
  }
  const int tx = t & 31, ty = t >> 5;
  const int bc = bx * 32, br = by * 32;
#pragma unroll
  for (int i = 0; i < 4; ++i)
    tile[ty + i * 8][tx] = in[(size_t)(br + ty + i * 8) * C + bc + tx];
  __syncthreads();
#pragma unroll
  for (int i = 0; i < 4; ++i)
    out[(size_t)(bc + ty + i * 8) * R + br + tx] = (f16)tile[tx][ty + i * 8];
}

// ---------------------------------------------------------------------------
// Fused QKV projection GEMM (R12-verified): counted-vmcnt double-buffered
// gload_lds pipeline, BK=32, source-side swizzle, XCD-chunked block order.
// ---------------------------------------------------------------------------
__global__ __launch_bounds__(256) void hgemm_qkv(
    const f16* __restrict__ A, const f16* __restrict__ Bt,
    const float* __restrict__ qb, const float* __restrict__ kb,
    const float* __restrict__ vb,
    f16* __restrict__ qf, f16* __restrict__ kf, f16* __restrict__ vf) {
  __shared__ f16 As[2 * 128 * 32];
  __shared__ f16 Bs[2 * 128 * 32];
  const int K = 1024;
  const int id = blockIdx.x;
  const int xcd = id & 7, loc = id >> 3;
  const int grp = loc >> 5, inn = loc & 31;
  const int bnT = grp * 4 + (inn >> 3);
  const int bm = (xcd * 8 + (inn & 7)) * 128;
  const int bn = bnT * 128;
  const int t = threadIdx.x;
  const int lane = t & 63, wave = t >> 6;
  const int wr = wave >> 1, wc = wave & 1;
  const int lrow = lane & 15, lk = lane >> 4;
  const int srow = lane >> 2;
  const int sblk = (lane & 3) ^ ((srow ^ (srow >> 2)) & 3);

  f32x4 acc[4][4];
#pragma unroll
  for (int i = 0; i < 4; ++i)
#pragma unroll
    for (int j = 0; j < 4; ++j) acc[i][j] = (f32x4)0.f;

  auto stage = [&](int buf, int ktile) {
#pragma unroll
    for (int i = 0; i < 2; ++i) {
      const int rr = (wave * 2 + i) * 16 + srow;
      GL16(A + (size_t)(bm + rr) * K + ktile * 32 + sblk * 8,
           (char*)As + buf * 8192 + (wave * 2 + i) * 1024);
      GL16(Bt + (size_t)(bn + rr) * K + ktile * 32 + sblk * 8,
           (char*)Bs + buf * 8192 + (wave * 2 + i) * 1024);
    }
  };

  stage(0, 0);
  for (int kt = 0; kt < 32; ++kt) {
    const int cur = kt & 1;
    stage(cur ^ 1, (kt + 1) & 31);
    asm volatile("s_waitcnt vmcnt(4)" ::: "memory");
    __builtin_amdgcn_s_barrier();
    __builtin_amdgcn_sched_barrier(0);
    h8 af[4], bf[4];
#pragma unroll
    for (int f = 0; f < 4; ++f) {
      const int ra = wr * 64 + f * 16 + lrow;
      af[f] = *(const h8*)((char*)As + cur * 8192 + ra * 64 +
                           ((lk ^ ((ra ^ (ra >> 2)) & 3)) << 4));
      const int rb = wc * 64 + f * 16 + lrow;
      bf[f] = *(const h8*)((char*)Bs + cur * 8192 + rb * 64 +
                           ((lk ^ ((rb ^ (rb >> 2)) & 3)) << 4));
    }
#pragma unroll
    for (int i2 = 0; i2 < 4; ++i2)
#pragma unroll
      for (int j = 0; j < 4; ++j)
        acc[i2][j] = __builtin_amdgcn_mfma_f32_16x16x32_f16(af[i2], bf[j], acc[i2][j], 0, 0, 0);
    asm volatile("s_waitcnt lgkmcnt(0)" ::: "memory");
    __builtin_amdgcn_sched_barrier(0);
    __builtin_amdgcn_s_barrier();
  }

  const float* bias;
  int nbase;
  if (bnT < 8) { bias = qb; nbase = 0; }
  else if (bnT < 16) { bias = kb; nbase = 1024; }
  else { bias = vb; nbase = 2048; }

#pragma unroll
  for (int fi = 0; fi < 4; ++fi) {
#pragma unroll
    for (int j = 0; j < 4; ++j) {
      const int grow = bm + wr * 64 + fi * 16 + lk * 4 + j;
      const int bb = grow >> 11, ss = grow & 2047;
#pragma unroll
      for (int fj = 0; fj < 4; ++fj) {
        const int gcol = bn + wc * 64 + fj * 16 + lrow;
        const int nl = gcol - nbase;
        const float g = acc[fi][fj][j] + bias[nl];
        if (bnT < 8) {
          qf[((size_t)(bb * 16 + (nl >> 6)) * 2048 + ss) * 64 + (nl & 63)] = (f16)g;
        } else if (bnT < 16) {
          kf[((size_t)(bb * 16 + (nl >> 6)) * 2048 + ss) * 64 + (nl & 63)] = (f16)g;
        } else {
          vf[((size_t)(bb * 16 + (nl >> 5)) * 2048 + ss) * 32 + (nl & 31)] = (f16)g;
        }
      }
    }
  }
}

// ---------------------------------------------------------------------------
// V transpose (R10-verified): vf [64][2048][32] -> vfT [64][32][2048].
// ---------------------------------------------------------------------------
__global__ __launch_bounds__(256) void transpose_v(
    const f16* __restrict__ vf, f16* __restrict__ vfT) {
  __shared__ f16 tl[32][36];
  const int bh = blockIdx.x >> 6;
  const int st = (blockIdx.x & 63) * 32;
  const int t = threadIdx.x;
  const int row = t >> 3, cq = t & 7;
  {
    const h4 v = *(const h4*)(vf + ((size_t)bh * 2048 + st + row) * 32 + cq * 4);
    *(h4*)&tl[row][cq * 4] = v;
  }
  __syncthreads();
  {
    h4 v;
#pragma unroll
    for (int e = 0; e < 4; ++e) v[e] = tl[cq * 4 + e][row];
    *(h4*)(vfT + ((size_t)bh * 32 + row) * 2048 + st + cq * 4) = v;
  }
}

// ---------------------------------------------------------------------------
// Output projection GEMM (R4-verified): out = attf @ owt^T + ob. fp32 out.
// ---------------------------------------------------------------------------
__global__ __launch_bounds__(256) void hgemm_out(
    const f16* __restrict__ A, const f16* __restrict__ Bt,
    const float* __restrict__ bias, float* __restrict__ outp,
    const int N, const int K) {
  __shared__ f16 As[128 * 40];
  __shared__ f16 Bs[128 * 40];
  const int id = blockIdx.x;
  const int swz = (id & 7) * 64 + (id >> 3);
  const int bn = (swz & 7) * 128;
  const int bm = (swz >> 3) * 128;
  const int t = threadIdx.x;
  const int lane = t & 63, wave = t >> 6;
  const int wr = wave >> 1, wc = wave & 1;
  const int lrow = lane & 15, lk = lane >> 4;

  f32x4 acc[4][4];
#pragma unroll
  for (int i = 0; i < 4; ++i)
#pragma unroll
    for (int j = 0; j < 4; ++j) acc[i][j] = (f32x4)0.f;

  for (int kt = 0; kt < K; kt += 32) {
#pragma unroll
    for (int i = 0; i < 2; ++i) {
      const int ch = t + i * 256;
      const int row = ch >> 2, part = ch & 3;
      *(u4*)&As[row * 40 + part * 8] =
          *(const u4*)(A + (size_t)(bm + row) * K + kt + part * 8);
      *(u4*)&Bs[row * 40 + part * 8] =
          *(const u4*)(Bt + (size_t)(bn + row) * K + kt + part * 8);
    }
    __syncthreads();
    h8 af[4], bf[4];
#pragma unroll
    for (int f = 0; f < 4; ++f) {
      af[f] = *(const h8*)&As[(wr * 64 + f * 16 + lrow) * 40 + lk * 8];
      bf[f] = *(const h8*)&Bs[(wc * 64 + f * 16 + lrow) * 40 + lk * 8];
    }
#pragma unroll
    for (int i = 0; i < 4; ++i)
#pragma unroll
      for (int j = 0; j < 4; ++j)
        acc[i][j] = __builtin_amdgcn_mfma_f32_16x16x32_f16(af[i], bf[j], acc[i][j], 0, 0, 0);
    __syncthreads();
  }

#pragma unroll
  for (int fi = 0; fi < 4; ++fi) {
#pragma unroll
    for (int j = 0; j < 4; ++j) {
      const int grow = bm + wr * 64 + fi * 16 + lk * 4 + j;
#pragma unroll
      for (int fj = 0; fj < 4; ++fj) {
        const int gcol = bn + wc * 64 + fj * 16 + lrow;
        outp[(size_t)grow * N + gcol] = acc[fi][fj][j] + bias[gcol];
      }
    }
  }
}

// ---------------------------------------------------------------------------
// MFMA causal flash attention (R12/R19 math; ONLY delta: K/V staging via
// global_load_lds with per-lane source-address swizzle — produces a
// bit-identical LDS image to R12's SWZ ds_writes, with no ds_write ops).
// qf/kf: [64][2048][64] f16; vfT: [64][32][2048] f16; attf: [8192][512] f16.
// ---------------------------------------------------------------------------
__global__ __launch_bounds__(256) void attn_mfma(
    const f16* __restrict__ qf, const f16* __restrict__ kf,
    const f16* __restrict__ vfT, f16* __restrict__ attf) {
  __shared__ f16 Ks[64 * 64];
  __shared__ f16 VsT[32 * 64];
  __shared__ f16 Ps[4 * 32 * 64];
  const int id = blockIdx.x;
  const int bh = id & 63;
  const int qblk = 15 - (id >> 6);
  const int qbase = qblk * 128;
  const int t = threadIdx.x;
  const int lane = t & 63, w = t >> 6;
  const int l15 = lane & 15, g = lane >> 4;
  const size_t kvbase = (size_t)bh * 2048;
  char* Pw = (char*)&Ps[w * 32 * 64];

  h8 ones;
#pragma unroll
  for (int e = 0; e < 8; ++e) ones[e] = (f16)1.0f;

  h8 qreg[2][2];
#pragma unroll
  for (int fj = 0; fj < 2; ++fj) {
    const int q = qbase + fj * 64 + w * 16 + l15;
#pragma unroll
    for (int ks = 0; ks < 2; ++ks) {
      h8 raw = *(const h8*)(qf + (kvbase + q) * 64 + ks * 32 + g * 8);
#pragma unroll
      for (int e = 0; e < 8; ++e) raw[e] = raw[e] * (f16)0.125f;
      qreg[fj][ks] = raw;
    }
  }

  f32x4 accO[2][2];
  f32x4 accL[2];
#pragma unroll
  for (int i = 0; i < 2; ++i) {
    accL[i] = (f32x4)0.f;
#pragma unroll
    for (int j = 0; j < 2; ++j) accO[i][j] = (f32x4)0.f;
  }
  float m2[2] = {-1.0e30f, -1.0e30f};

  const int ntiles = qblk * 2 + 2;
  for (int kt = 0; kt < ntiles; ++kt) {
    const int kbase = kt * 64;
    __syncthreads();  // prior tile's LDS reads complete
    // --- K: 8 x 1KB chunks (2 per wave); lane covers (row, slot sch) and
    //     reads global block sch ^ swz7(row) -> LDS image == R12's SWZ writes.
#pragma unroll
    for (int i = 0; i < 2; ++i) {
      const int chunk = w * 2 + i;              // 0..7
      const int row = chunk * 8 + (lane >> 3);  // 0..63
      const int srcb = (lane & 7) ^ ((row ^ (row >> 3)) & 7);
      GL16(kf + (kvbase + kbase + row) * 64 + srcb * 8,
           (char*)Ks + chunk * 1024);
    }
    {  // --- V^T: 4 x 1KB chunks (1 per wave)
      const int vrow = w * 8 + (lane >> 3);     // 0..31
      const int vsrcb = (lane & 7) ^ ((vrow ^ (vrow >> 3)) & 7);
      GL16(vfT + ((size_t)bh * 32 + vrow) * 2048 + kbase + vsrcb * 8,
           (char*)VsT + w * 1024);
    }
    __syncthreads();  // drains vmcnt -> staged data visible

    f32x4 accS[4][2];
#pragma unroll
    for (int i = 0; i < 4; ++i)
#pragma unroll
      for (int j = 0; j < 2; ++j) accS[i][j] = (f32x4)0.f;
#pragma unroll
    for (int ks = 0; ks < 2; ++ks) {
#pragma unroll
      for (int fim = 0; fim < 4; ++fim) {
        const h8 af = *(const h8*)((char*)Ks + SWZ(fim * 16 + l15, ks * 64 + g * 16));
#pragma unroll
        for (int fj = 0; fj < 2; ++fj)
          accS[fim][fj] = __builtin_amdgcn_mfma_f32_16x16x32_f16(af, qreg[fj][ks], accS[fim][fj], 0, 0, 0);
      }
    }

#pragma unroll
    for (int fj = 0; fj < 2; ++fj) {
      const int qg = qbase + fj * 64 + w * 16 + l15;
      const bool need_mask = (kbase + 63 > qbase + fj * 64 + w * 16);
      float sc[4][4];
#pragma unroll
      for (int fim = 0; fim < 4; ++fim)
#pragma unroll
        for (int j = 0; j < 4; ++j) {
          float v = accS[fim][fj][j];
          if (need_mask) {
            const int key = kbase + fim * 16 + g * 4 + j;
            v = (key <= qg) ? v : -1.0e30f;
          }
          sc[fim][j] = v;
        }
      const float a0 = fmaxf(fmaxf(sc[0][0], sc[0][1]), sc[0][2]);
      const float a1 = fmaxf(fmaxf(sc[0][3], sc[1][0]), sc[1][1]);
      const float a2 = fmaxf(fmaxf(sc[1][2], sc[1][3]), sc[2][0]);
      const float a3 = fmaxf(fmaxf(sc[2][1], sc[2][2]), sc[2][3]);
      const float a4 = fmaxf(fmaxf(sc[3][0], sc[3][1]), sc[3][2]);
      float mc = fmaxf(fmaxf(fmaxf(a0, a1), a2),
                       fmaxf(fmaxf(a3, a4), sc[3][3]));
      mc = fmaxf(mc, __shfl_xor(mc, 16));
      mc = fmaxf(mc, __shfl_xor(mc, 32));
      if (!__all(mc <= m2[fj] + 1.5f)) {
        const float mnew = fmaxf(m2[fj], mc);
        const float corr = __expf(m2[fj] - mnew);
        m2[fj] = mnew;
#pragma unroll
        for (int j = 0; j < 4; ++j) {
          const float c = __shfl(corr, g * 4 + j);
          accO[fj][0][j] *= c;
          accO[fj][1][j] *= c;
          accL[fj][j] *= c;
        }
      }
      const float nml = -m2[fj] * L2E;
#pragma unroll
      for (int fim = 0; fim < 4; ++fim) {
        h4 hp;
#pragma unroll
        for (int j = 0; j < 4; ++j)
          hp[j] = (f16)EXP2F(fmaf(sc[fim][j], L2E, nml));
        *(h4*)(Pw + SWZ(fj * 16 + l15, fim * 32 + g * 8)) = hp;
      }
    }

#pragma unroll
    for (int ks = 0; ks < 2; ++ks) {
      const h8 pa0 = *(const h8*)(Pw + SWZ(l15, ks * 64 + g * 16));
      const h8 pa1 = *(const h8*)(Pw + SWZ(16 + l15, ks * 64 + g * 16));
#pragma unroll
      for (int fr = 0; fr < 2; ++fr) {
        const h8 vb = *(const h8*)((char*)VsT + SWZ(fr * 16 + l15, ks * 64 + g * 16));
        accO[0][fr] = __builtin_amdgcn_mfma_f32_16x16x32_f16(pa0, vb, accO[0][fr], 0, 0, 0);
        accO[1][fr] = __builtin_amdgcn_mfma_f32_16x16x32_f16(pa1, vb, accO[1][fr], 0, 0, 0);
      }
      accL[0] = __builtin_amdgcn_mfma_f32_16x16x32_f16(pa0, ones, accL[0], 0, 0, 0);
      accL[1] = __builtin_amdgcn_mfma_f32_16x16x32_f16(pa1, ones, accL[1], 0, 0, 0);
    }
  }

  const int b = bh >> 4, h = bh & 15;
#pragma unroll
  for (int fo = 0; fo < 2; ++fo) {
#pragma unroll
    for (int j = 0; j < 4; ++j) {
      const float iv = 1.f / accL[fo][j];
      const int q = qbase + fo * 64 + w * 16 + g * 4 + j;
#pragma unroll
      for (int fr = 0; fr < 2; ++fr) {
        const int r = fr * 16 + l15;
        attf[((size_t)b * 2048 + q) * 512 + h * 32 + r] = (f16)(accO[fo][fr][j] * iv);
      }
    }
  }
}

// ---------------------------------------------------------------------------
extern "C" void kernel_launch(void* const* d_in, const int* in_sizes, int n_in,
                              void* d_out, int out_size, void* d_ws, size_t ws_size,
                              hipStream_t stream) {
  const float* hs = (const float*)d_in[0];
  const float* qw = (const float*)d_in[1];
  const float* qb = (const float*)d_in[2];
  const float* kw = (const float*)d_in[3];
  const float* kb = (const float*)d_in[4];
  const float* vw = (const float*)d_in[5];
  const float* vb = (const float*)d_in[6];
  const float* ow = (const float*)d_in[7];
  const float* ob = (const float*)d_in[8];
  float* out = (float*)d_out;
  char* ws = (char*)d_ws;

  // Scratch (MB offsets), 80 MB total (ws >= 96 MB proven in R3):
  f16* qf = (f16*)(ws);                         // 16 MB [64][2048][64]
  f16* kf = (f16*)(ws + ((size_t)16 << 20));    // 16 MB
  f16* vf = (f16*)(ws + ((size_t)32 << 20));    //  8 MB [64][2048][32]
  f16* vfT = (f16*)(ws + ((size_t)72 << 20));   //  8 MB [64][32][2048]
  f16* attf = (f16*)(ws + ((size_t)40 << 20));  //  8 MB [8192][512]
  f16* wqkv = (f16*)(ws + ((size_t)48 << 20));  //  5 MB [2560][1024]
  f16* owt = (f16*)(ws + ((size_t)53 << 20));   //  1 MB [1024][512]
  f16* hsf = (f16*)(ws + ((size_t)56 << 20));   // 16 MB [8192][1024]

  prep<<<dim3(5120), 256, 0, stream>>>(hs, hsf, qw, kw, vw, ow, wqkv, owt);
  hgemm_qkv<<<dim3(1280), 256, 0, stream>>>(hsf, wqkv, qb, kb, vb, qf, kf, vf);
  transpose_v<<<dim3(4096), 256, 0, stream>>>(vf, vfT);
  attn_mfma<<<dim3(1024), 256, 0, stream>>>(qf, kf, vfT, attf);
  hgemm_out<<<dim3(512), 256, 0, stream>>>(attf, owt, ob, out, 1024, 512);
}